// Round 11
// baseline (1090.411 us; speedup 1.0000x reference)
//
#include <hip/hip_runtime.h>

// KAN FFN on MI355X. out = KAN2(KAN1(x)); each KAN linear is a bf16 GEMM over
// [silu(u) | cubic b-spline bases(u)] vs [base_w | spline_w*scaler].
//
// This version NEVER materializes act2 (the 302 MB layer-2 activation):
//   gemm1 (gemm256<4>): h = act1 x W1aug^T; epilogue stores h (fp32) and
//     silu(h) (bf16, compact 4096x4096).
//   G2a (gemm256<0>):  zbuf  = silu(h) x bw2^T      (K=4096, split-K z=4)
//   G2b (gemm_bas):    zbuf += bases(h) x sw2'^T    (K=32768, split-K z=4,
//     A-tiles built on the fly inside the K-loop: 1 dwordx4 of h per thread
//     per tile -> 4x bases8 VALU -> 4x swizzled ds_write_b128).
//   reduce4: out = sum of 4 z-slices.
// GEMM core: 256x256 tile, BK=64 in two K-halves, 8 waves, 4 phases/K-tile,
// counted vmcnt (never 0 in main loop), XOR swizzle on 16B units, setprio,
// bijective XCD block swizzle.
//
// ws layout (needs 251,658,240 B; fallback Tier C below):
//   [0, 75.5M)      act1 -> w2
//   [75.5M, 151M)   w1   -> zbuf (67 MB)
//   [151M, 218.1M)  h    (fp32 4096x4096)
//   [218.1M, 251.7M) siluBuf (bf16 4096x4096)

typedef unsigned short u16;
typedef __bf16 bf16x8 __attribute__((ext_vector_type(8)));
typedef float f32x4 __attribute__((ext_vector_type(4)));
typedef u16 u16x8 __attribute__((ext_vector_type(8)));

#define D_MODEL 1024
#define D_FF    4096
#define NTOK    4096
#define K1      9216    // 9*1024
#define K2      36864   // 9*4096
#define KCHUNK  9216

__device__ __forceinline__ u16 f2bf(float v) {
    union { float f; unsigned u; } a; a.f = v;
    unsigned r = a.u + 0x7FFFu + ((a.u >> 16) & 1u);  // RNE
    return (u16)(r >> 16);
}

__device__ __forceinline__ float silu_f(float x) {
    return x / (1.f + __expf(-x));
}

// cubic b-spline bases (grid 5, order 3): 8 bf16 coefficients for one x
__device__ __forceinline__ u16x8 bases8(float xv) {
    const float t = (xv + 2.2f) * 2.5f;               // knot units
    const bool inr = (t >= 0.f) && (t < 11.f);
    const float jf = floorf(t);
    const int j = (int)jf;
    const float f = t - jf;
    const float f2 = f * f, f3 = f2 * f;
    const float s6 = 1.f / 6.f;
    const float w3 = f3 * s6;
    const float w2 = (1.f + 3.f*f + 3.f*f2 - 3.f*f3) * s6;
    const float w1 = (4.f - 6.f*f2 + 3.f*f3) * s6;
    float w0 = 1.f - f; w0 = w0 * w0 * w0 * s6;
    u16x8 p;
#pragma unroll
    for (int c = 0; c < 8; ++c) {
        float v = 0.f;
        v = (j == c)     ? w3 : v;
        v = (j == c + 1) ? w2 : v;
        v = (j == c + 2) ? w1 : v;
        v = (j == c + 3) ? w0 : v;
        v = inr ? v : 0.f;
        p[c] = f2bf(v);
    }
    return p;
}

__device__ __forceinline__ void llds16(const u16* g, u16* l) {
    __builtin_amdgcn_global_load_lds(
        (__attribute__((address_space(1))) void*)(u16*)g,
        (__attribute__((address_space(3))) void*)l,
        16, 0, 0);
}

// ---------------------------------------------------------------------------
__global__ __launch_bounds__(256) void build_w(
    const float* __restrict__ bw, const float* __restrict__ sw,
    const float* __restrict__ sc, u16* __restrict__ dst,
    int IN, int shift)
{
    const int idx = blockIdx.x * 256 + threadIdx.x;      // o*IN + i
    const int o = idx >> shift;
    const int i = idx & (IN - 1);
    const int rowLen = IN * 9;
    const float scv = sc[idx];
    const float* sp = sw + (size_t)idx * 8;
    f32x4 s0 = *(const f32x4*)sp;
    f32x4 s1 = *(const f32x4*)(sp + 4);
    u16x8 p;
#pragma unroll
    for (int t = 0; t < 4; ++t) {
        p[t]     = f2bf(s0[t] * scv);
        p[t + 4] = f2bf(s1[t] * scv);
    }
    dst[(size_t)o * rowLen + i] = f2bf(bw[idx]);
    *(u16x8*)(dst + (size_t)o * rowLen + IN + (size_t)i * 8) = p;
}

// ---------------------------------------------------------------------------
__global__ __launch_bounds__(128) void build_act(
    const float* __restrict__ src, int srcCols,
    u16* __restrict__ dst, int col0, int ldDst)
{
    const int g = blockIdx.x * 128 + threadIdx.x;        // group of 8 cols
    const int n = blockIdx.y;
    const int base = col0 + g * 8;
    u16x8 p;
    if (base < srcCols) {
        const float* sp = src + (size_t)n * srcCols + base;
        f32x4 v0 = *(const f32x4*)sp;
        f32x4 v1 = *(const f32x4*)(sp + 4);
#pragma unroll
        for (int t = 0; t < 4; ++t) {
            p[t]     = f2bf(silu_f(v0[t]));
            p[t + 4] = f2bf(silu_f(v1[t]));
        }
    } else {
        const int i = (base - srcCols) >> 3;
        p = bases8(src[(size_t)n * srcCols + i]);
    }
    *(u16x8*)(dst + (size_t)n * ldDst + (size_t)g * 8) = p;
}

// ---------------------------------------------------------------------------
// C[M,N] = A[M,K]*B[N,K]^T (bf16 in, fp32 out). 256x256 tile, BK=64.
// WMODE: 0 store | 1 atomicAdd | 2 load-add-store | 4 store h fp32 (into C,
// ldc=4096) AND silu(h) bf16 (into actOut, lda 4096).
template <int WMODE>
__global__ __launch_bounds__(512, 2) void gemm256(
    const u16* __restrict__ A, int lda,
    const u16* __restrict__ B, int ldb,
    float* __restrict__ C, int ldc,
    int nk, size_t zstride, u16* __restrict__ actOut)
{
    __shared__ __attribute__((aligned(16))) u16 sm[2][2][2][256][32];

    const int tid  = threadIdx.x;
    const int lane = tid & 63;
    const int wave = tid >> 6;
    const int wr = wave >> 2;
    const int wc = wave & 3;

    const int gx = gridDim.x, gy = gridDim.y, gz = gridDim.z;
    int flat = (blockIdx.z * gy + blockIdx.y) * gx + blockIdx.x;
    const int nwg = gx * gy * gz;
    const int cpx = nwg >> 3;
    flat = (flat & 7) * cpx + (flat >> 3);
    const int bx = flat % gx;
    const int by = (flat / gx) % gy;
    const int bz = flat / (gx * gy);

    const int m0 = by * 256;
    const int n0 = bx * 256;
    const int k0 = bz * nk * 64;

    const int sRow  = tid >> 2;
    const int swcol = ((tid & 3) ^ ((tid >> 3) & 3)) * 8;
    const u16* Ag0 = A + (size_t)(m0 + sRow)       * lda + k0 + swcol;
    const u16* Ag1 = A + (size_t)(m0 + 128 + sRow) * lda + k0 + swcol;
    const u16* Bg0 = B + (size_t)(n0 + sRow)       * ldb + k0 + swcol;
    const u16* Bg1 = B + (size_t)(n0 + 128 + sRow) * ldb + k0 + swcol;

    const int fRow = lane & 15;
    const int ucol = (((lane >> 4) ^ ((lane >> 1) & 3))) * 8;

    const f32x4 zero = {0.f, 0.f, 0.f, 0.f};
    f32x4 acc[8][4];
#pragma unroll
    for (int a = 0; a < 8; ++a)
#pragma unroll
        for (int b = 0; b < 4; ++b) acc[a][b] = zero;

#pragma unroll
    for (int p = 0; p < 4; ++p) {
        const size_t koff = (size_t)(p >> 1) * 32;
        u16* lb = &sm[0][p & 1][p >> 1][0][0] + wave * 512;
        if ((p & 1) == 0) { llds16(Ag0 + koff, lb); llds16(Ag1 + koff, lb + 4096); }
        else              { llds16(Bg0 + koff, lb); llds16(Bg1 + koff, lb + 4096); }
    }
    asm volatile("s_waitcnt vmcnt(4)" ::: "memory");
    __builtin_amdgcn_s_barrier();
    __builtin_amdgcn_sched_barrier(0);

    bf16x8 bb[4];
    for (int kt = 0; kt < nk; ++kt) {
        const int b = kt & 1;
        const int ktn = (kt + 1 < nk) ? kt + 1 : 0;
#pragma unroll
        for (int p = 0; p < 4; ++p) {
            const int ks = p >> 1, mh = p & 1;
            bf16x8 af[4];
#pragma unroll
            for (int j = 0; j < 4; ++j)
                af[j] = *(const bf16x8*)
                    &sm[b][0][ks][wr * 128 + mh * 64 + j * 16 + fRow][ucol];
            if (mh == 0) {
#pragma unroll
                for (int nf = 0; nf < 4; ++nf)
                    bb[nf] = *(const bf16x8*)
                        &sm[b][1][ks][wc * 64 + nf * 16 + fRow][ucol];
            }
            {
                const size_t koff = (size_t)ktn * 64 + (size_t)(p >> 1) * 32;
                u16* lb = &sm[b ^ 1][p & 1][p >> 1][0][0] + wave * 512;
                if ((p & 1) == 0) { llds16(Ag0 + koff, lb); llds16(Ag1 + koff, lb + 4096); }
                else              { llds16(Bg0 + koff, lb); llds16(Bg1 + koff, lb + 4096); }
            }
            asm volatile("s_waitcnt lgkmcnt(0)" ::: "memory");
            __builtin_amdgcn_sched_barrier(0);
            __builtin_amdgcn_s_setprio(1);
#pragma unroll
            for (int j = 0; j < 4; ++j)
#pragma unroll
                for (int nf = 0; nf < 4; ++nf)
                    acc[mh * 4 + j][nf] = __builtin_amdgcn_mfma_f32_16x16x32_bf16(
                        af[j], bb[nf], acc[mh * 4 + j][nf], 0, 0, 0);
            __builtin_amdgcn_s_setprio(0);
            __builtin_amdgcn_sched_barrier(0);
            if (p == 1 || p == 3)
                asm volatile("s_waitcnt vmcnt(4)" ::: "memory");
            __builtin_amdgcn_s_barrier();
            __builtin_amdgcn_sched_barrier(0);
        }
    }
    asm volatile("s_waitcnt vmcnt(0)" ::: "memory");

    const int cRow = m0 + wr * 128 + (lane >> 4) * 4;
    const int cCol = n0 + wc * 64 + (lane & 15);
    if (WMODE == 4) {
#pragma unroll
        for (int af = 0; af < 8; ++af)
#pragma unroll
            for (int nf = 0; nf < 4; ++nf)
#pragma unroll
                for (int j = 0; j < 4; ++j) {
                    const int row = cRow + af * 16 + j;
                    const int col = cCol + nf * 16;
                    const float v = acc[af][nf][j];
                    C[(size_t)row * ldc + col] = v;                 // h fp32
                    actOut[(size_t)row * 4096 + col] = f2bf(silu_f(v));
                }
    } else {
        float* Cz = C + (size_t)bz * zstride;
#pragma unroll
        for (int af = 0; af < 8; ++af)
#pragma unroll
            for (int nf = 0; nf < 4; ++nf)
#pragma unroll
                for (int j = 0; j < 4; ++j) {
                    const size_t off = (size_t)(cRow + af * 16 + j) * ldc
                                     + (cCol + nf * 16);
                    if (WMODE == 1)      atomicAdd(&Cz[off], acc[af][nf][j]);
                    else if (WMODE == 2) Cz[off] += acc[af][nf][j];
                    else                 Cz[off] = acc[af][nf][j];
                }
    }
}

// ---------------------------------------------------------------------------
// zbuf(bz) += bases(h) x B^T over the 32768-wide basis region.
// A-tiles built on the fly: per K-tile (64 basis cols = 8 h cols), thread t
// loads h[m0 + (t>>1)][hc0 + (t&1)*4 ..+3] (one dwordx4), computes 4x bases8,
// ds_writes 4x b128 into the swizzled A slot of the next LDS buffer.
// vmem ledger/tile: 1 h-load (p0) + 2 B-kh0 (p1) + 2 B-kh1 (p3) = 5.
// Waits: p1-end vmcnt(3) [B-kh1(t) landed for p2 reads], p2 vmcnt(2)
// [h landed, pre-VALU], p3-end vmcnt(2) [B-kh0(t+1) landed for next p0].
__global__ __launch_bounds__(512, 2) void gemm_bas(
    const float* __restrict__ h,
    const u16* __restrict__ B, int ldb,
    float* __restrict__ C, int ldc,
    int nk, size_t zstride)
{
    __shared__ __attribute__((aligned(16))) u16 sm[2][2][2][256][32];

    const int tid  = threadIdx.x;
    const int lane = tid & 63;
    const int wave = tid >> 6;
    const int wr = wave >> 2;
    const int wc = wave & 3;

    const int gx = gridDim.x, gy = gridDim.y, gz = gridDim.z;
    int flat = (blockIdx.z * gy + blockIdx.y) * gx + blockIdx.x;
    const int nwg = gx * gy * gz;
    const int cpx = nwg >> 3;
    flat = (flat & 7) * cpx + (flat >> 3);
    const int bx = flat % gx;
    const int by = (flat / gx) % gy;
    const int bz = flat / (gx * gy);

    const int m0 = by * 256;
    const int n0 = bx * 256;
    const int kb0 = bz * nk * 64;                    // basis-col offset

    // B staging (identical mechanics to gemm256)
    const int sRow  = tid >> 2;
    const int swcol = ((tid & 3) ^ ((tid >> 3) & 3)) * 8;
    const u16* Bg0 = B + (size_t)(n0 + sRow)       * ldb + kb0 + swcol;
    const u16* Bg1 = B + (size_t)(n0 + 128 + sRow) * ldb + kb0 + swcol;

    // A source: h slab. thread t -> row t>>1, K-half t&1.
    const int hr = tid >> 1;
    const int hh = tid & 1;
    const float* Hg = h + (size_t)(m0 + hr) * 4096 + (kb0 >> 3) + hh * 4;
    const int wu = (hr >> 1) & 3;                    // XOR key for writes
    u16* dwA[2] = { &sm[0][0][hh][hr][0], &sm[1][0][hh][hr][0] };

    const int fRow = lane & 15;
    const int ucol = (((lane >> 4) ^ ((lane >> 1) & 3))) * 8;

    const f32x4 zero = {0.f, 0.f, 0.f, 0.f};
    f32x4 acc[8][4];
#pragma unroll
    for (int a = 0; a < 8; ++a)
#pragma unroll
        for (int b = 0; b < 4; ++b) acc[a][b] = zero;

    // prologue: tile 0 -> buf 0 (drain fully once)
    f32x4 hv = *(const f32x4*)Hg;
    { u16* lb = &sm[0][1][0][0][0] + wave * 512;
      llds16(Bg0, lb); llds16(Bg1, lb + 4096); }
    { u16* lb = &sm[0][1][1][0][0] + wave * 512;
      llds16(Bg0 + 32, lb); llds16(Bg1 + 32, lb + 4096); }
    asm volatile("s_waitcnt vmcnt(4)" ::: "memory");
    __builtin_amdgcn_sched_barrier(0);
#pragma unroll
    for (int i = 0; i < 4; ++i) {
        u16x8 bs = bases8(hv[i]);
        *(u16x8*)(dwA[0] + (size_t)((i ^ wu) * 8)) = bs;
    }
    asm volatile("s_waitcnt vmcnt(0) lgkmcnt(0)" ::: "memory");
    __builtin_amdgcn_s_barrier();
    __builtin_amdgcn_sched_barrier(0);

    bf16x8 bb[4];
    for (int kt = 0; kt < nk; ++kt) {
        const int b = kt & 1;
        const int ktn = (kt + 1 < nk) ? kt + 1 : 0;  // wrap keeps counts uniform
        u16* dwN = dwA[b ^ 1];
#pragma unroll
        for (int p = 0; p < 4; ++p) {
            const int ks = p >> 1, mh = p & 1;
            bf16x8 af[4];
#pragma unroll
            for (int j = 0; j < 4; ++j)
                af[j] = *(const bf16x8*)
                    &sm[b][0][ks][wr * 128 + mh * 64 + j * 16 + fRow][ucol];
            if (mh == 0) {
#pragma unroll
                for (int nf = 0; nf < 4; ++nf)
                    bb[nf] = *(const bf16x8*)
                        &sm[b][1][ks][wc * 64 + nf * 16 + fRow][ucol];
            }
            if (p == 0)
                hv = *(const f32x4*)(Hg + (size_t)ktn * 8);
            if (p == 1) {
                u16* lb = &sm[b ^ 1][1][0][0][0] + wave * 512;
                llds16(Bg0 + (size_t)ktn * 64, lb);
                llds16(Bg1 + (size_t)ktn * 64, lb + 4096);
            }
            if (p == 2) {
                asm volatile("s_waitcnt vmcnt(2)" ::: "memory");
                __builtin_amdgcn_sched_barrier(0);
#pragma unroll
                for (int i = 0; i < 4; ++i) {
                    u16x8 bs = bases8(hv[i]);
                    *(u16x8*)(dwN + (size_t)((i ^ wu) * 8)) = bs;
                }
            }
            if (p == 3) {
                u16* lb = &sm[b ^ 1][1][1][0][0] + wave * 512;
                llds16(Bg0 + (size_t)ktn * 64 + 32, lb);
                llds16(Bg1 + (size_t)ktn * 64 + 32, lb + 4096);
            }
            __builtin_amdgcn_s_barrier();
            asm volatile("s_waitcnt lgkmcnt(0)" ::: "memory");
            __builtin_amdgcn_sched_barrier(0);
            __builtin_amdgcn_s_setprio(1);
#pragma unroll
            for (int j = 0; j < 4; ++j)
#pragma unroll
                for (int nf = 0; nf < 4; ++nf)
                    acc[mh * 4 + j][nf] = __builtin_amdgcn_mfma_f32_16x16x32_bf16(
                        af[j], bb[nf], acc[mh * 4 + j][nf], 0, 0, 0);
            __builtin_amdgcn_s_setprio(0);
            __builtin_amdgcn_sched_barrier(0);
            if (p == 1)
                asm volatile("s_waitcnt vmcnt(3)" ::: "memory");
            if (p == 3)
                asm volatile("s_waitcnt vmcnt(2)" ::: "memory");
            __builtin_amdgcn_s_barrier();
            __builtin_amdgcn_sched_barrier(0);
        }
    }
    asm volatile("s_waitcnt vmcnt(0)" ::: "memory");

    // epilogue: accumulate into zbuf slice bz
    float* Cz = C + (size_t)bz * zstride;
    const int cRow = m0 + wr * 128 + (lane >> 4) * 4;
    const int cCol = n0 + wc * 64 + (lane & 15);
#pragma unroll
    for (int af = 0; af < 8; ++af)
#pragma unroll
        for (int nf = 0; nf < 4; ++nf)
#pragma unroll
            for (int j = 0; j < 4; ++j) {
                const size_t off = (size_t)(cRow + af * 16 + j) * ldc
                                 + (cCol + nf * 16);
                Cz[off] += acc[af][nf][j];
            }
}

// ---------------------------------------------------------------------------
__global__ __launch_bounds__(256) void reduce4(
    const float* __restrict__ z, float* __restrict__ out, int n4, int zstride4)
{
    const int i = blockIdx.x * 256 + threadIdx.x;
    if (i >= n4) return;
    const f32x4* p = (const f32x4*)z;
    f32x4 v = p[i];
    v += p[i + zstride4];
    v += p[i + 2 * zstride4];
    v += p[i + 3 * zstride4];
    *(f32x4*)(out + (size_t)i * 4) = v;
}

// ---------------------------------------------------------------------------
extern "C" void kernel_launch(void* const* d_in, const int* in_sizes, int n_in,
                              void* d_out, int out_size, void* d_ws, size_t ws_size,
                              hipStream_t stream) {
    const float* x   = (const float*)d_in[0];
    const float* bw1 = (const float*)d_in[1];
    const float* sw1 = (const float*)d_in[2];
    const float* sc1 = (const float*)d_in[3];
    const float* bw2 = (const float*)d_in[4];
    const float* sw2 = (const float*)d_in[5];
    const float* sc2 = (const float*)d_in[6];
    float* out = (float*)d_out;

    char* ws = (char*)d_ws;
    const size_t ZS = (size_t)NTOK * D_MODEL;             // 4,194,304 elems

    if (ws_size >= 251658240ull) {
        u16*   r0   = (u16*)ws;                           // act1 -> w2
        u16*   r1   = (u16*)(ws + 75497472);              // w1 -> zbuf
        float* zbuf = (float*)(ws + 75497472);
        float* hbuf = (float*)(ws + 150994944);           // h fp32
        u16*   silu = (u16*)(ws + 218103808);             // silu(h) bf16

        // ---- layer 1: h + silu(h) ----
        build_w<<<16384, 256, 0, stream>>>(bw1, sw1, sc1, r1, D_MODEL, 10);
        build_act<<<dim3(9, NTOK), 128, 0, stream>>>(x, D_MODEL, r0, 0, K1);
        gemm256<4><<<dim3(16, 16, 1), 512, 0, stream>>>(
            r0, K1, r1, K1, hbuf, D_FF, 144, 0, silu);

        // ---- layer 2 ----
        build_w<<<16384, 256, 0, stream>>>(bw2, sw2, sc2, r0, D_FF, 12);
        // G2a: silu part, K=4096 (z=4 x nk=16), store into zbuf slices
        gemm256<0><<<dim3(4, 16, 4), 512, 0, stream>>>(
            silu, D_FF, r0, K2, zbuf, D_MODEL, 16, ZS, nullptr);
        // G2b: basis part, K=32768 (z=4 x nk=128), accumulate into zbuf
        gemm_bas<<<dim3(4, 16, 4), 512, 0, stream>>>(
            hbuf, r0 + D_FF, K2, zbuf, D_MODEL, 128, ZS);
        reduce4<<<(int)(ZS / 4 / 256), 256, 0, stream>>>(
            zbuf, out, (int)(ZS / 4), (int)(ZS / 4));
        return;
    }

    // ---- Tier C fallback: chunked with atomics (round-3 structure) ----
    u16*   regionA = (u16*)ws;
    u16*   regionB = (u16*)(ws + 75497472);
    float* hbuf    = (float*)(ws + 150994944);

    hipMemsetAsync(d_out, 0, ZS * sizeof(float), stream);

    build_w<<<16384, 256, 0, stream>>>(bw1, sw1, sc1, regionA, D_MODEL, 10);
    build_act<<<dim3(9, NTOK), 128, 0, stream>>>(x, D_MODEL, regionB, 0, K1);
    gemm256<0><<<dim3(16, 16, 1), 512, 0, stream>>>(
        regionB, K1, regionA, K1, hbuf, D_FF, 144, 0, nullptr);

    build_w<<<16384, 256, 0, stream>>>(bw2, sw2, sc2, regionB, D_FF, 12);
    for (int ck = 0; ck < 4; ++ck) {
        build_act<<<dim3(9, NTOK), 128, 0, stream>>>(hbuf, D_FF, regionA, ck * KCHUNK, K1);
        gemm256<1><<<dim3(4, 16, 4), 512, 0, stream>>>(
            regionA, KCHUNK, regionB + (size_t)ck * KCHUNK, K2,
            out, D_MODEL, 36, ZS, nullptr);
    }
}